// Round 2
// baseline (122.144 us; speedup 1.0000x reference)
//
#include <hip/hip_runtime.h>
#include <math.h>

// Problem constants
#define DIM   256
#define NST   256
#define LSEQ  512
#define BAT   2
#define DTSZ  64
#define PCOLS 576
#define NROWS 1024

constexpr float LOG2E = 1.4426950408889634f;

__device__ __forceinline__ float fexp2(float v) {
#if __has_builtin(__builtin_amdgcn_exp2f)
    return __builtin_amdgcn_exp2f(v);
#else
    return exp2f(v);
#endif
}

__device__ __forceinline__ float softplusf(float v) {
    return (v > 20.f) ? v : log1pf(__expf(v));
}

// LDS-only barrier (kept from R12 — harmless, occasionally helps scheduling).
__device__ __forceinline__ void barrier_lds_only() {
    __builtin_amdgcn_s_waitcnt(0xC07F);   // vmcnt=63, expcnt=7, lgkmcnt=0
    __builtin_amdgcn_s_barrier();
}

// Pack (beta, gamma) as bf16x2 in one dword: beta lo16, gamma hi16. RNE.
__device__ __forceinline__ unsigned pack_bg(float be, float ga) {
    unsigned ub = __float_as_uint(be);
    unsigned ug = __float_as_uint(ga);
    ub = (ub + 0x7fffu + ((ub >> 16) & 1u)) >> 16;
    ug = (ug + 0x7fffu + ((ug >> 16) & 1u)) & 0xffff0000u;
    return ub | ug;
}

// Wave-uniform register broadcast: read lane l of v (l uniform).
__device__ __forceinline__ float rdlane(float v, int l) {
    return __uint_as_float((unsigned)__builtin_amdgcn_readlane(
        (int)__float_as_uint(v), l));
}

// ---------------- proj v2: readlane-broadcast fp32 GEMM.
// 256 blocks x 576 threads (9 waves). Block owns rows r0..r0+3; col = tid.
// A (4 x-rows) in registers, broadcast across the wave via v_readlane
// (SGPR-indexed, no LDS). B (W_in) streamed from L2: 1 coalesced dword per
// k per wave, reused by 4 rows in registers. W_in L2 traffic: 256 blocks x
// 576KB = 147MB (~4.3us floor), vs old 512x576KB = 295MB with 2 rows reuse.
// Epilogue: acc -> 9KB LDS, then waves 0-3 do dt GEMM (same readlane
// pattern) + softplus + dtp/dtxp while waves 4-7 pack betgam.
__global__ __launch_bounds__(576) void proj_kernel(
    const float* __restrict__ x, const float* __restrict__ W_in,
    const float* __restrict__ W_dt, const float* __restrict__ b_dt,
    unsigned* __restrict__ betgam,     // [NROWS, NST] bf16x2
    float* __restrict__ dtp, float* __restrict__ dtxp)
{
    __shared__ float Ls[4][PCOLS];          // 9216 B
    const int tid  = threadIdx.x;           // == column in [0, 576)
    const int lane = tid & 63;
    const int r0   = blockIdx.x * 4;

    // A rows r0..r0+3 into registers: vA[r][q] holds x[r0+r][q*64 + lane].
    // Static indices only (runtime-indexed reg arrays demote to scratch).
    float vA[4][4];
    #pragma unroll
    for (int r = 0; r < 4; ++r) {
        #pragma unroll
        for (int q = 0; q < 4; ++q)
            vA[r][q] = x[(r0 + r) * DIM + q * 64 + lane];
    }

    float acc[4] = {0.f, 0.f, 0.f, 0.f};
    const float* wp = W_in + tid;
    #pragma unroll
    for (int q = 0; q < 4; ++q) {           // q static -> vA[r][q] static
        #pragma unroll 8
        for (int kl = 0; kl < 64; ++kl) {   // kl uniform -> SGPR readlane idx
            const float bw = wp[(q * 64 + kl) * PCOLS];
            #pragma unroll
            for (int r = 0; r < 4; ++r)
                acc[r] = fmaf(rdlane(vA[r][q], kl), bw, acc[r]);
        }
    }

    #pragma unroll
    for (int r = 0; r < 4; ++r) Ls[r][tid] = acc[r];
    __syncthreads();

    if (tid < 256) {
        // dt path: d = tid. dt_raw = Ls[r][0..63] -> regs, readlane-broadcast.
        const int d = tid;
        float vD[4];
        #pragma unroll
        for (int r = 0; r < 4; ++r) vD[r] = Ls[r][lane];   // lane in [0,64)

        const float bd = b_dt[d];
        float accd[4] = {bd, bd, bd, bd};
        const float* wdp = W_dt + d;
        #pragma unroll 8
        for (int k = 0; k < DTSZ; ++k) {
            const float wv = wdp[k * DIM];
            #pragma unroll
            for (int r = 0; r < 4; ++r)
                accd[r] = fmaf(rdlane(vD[r], k), wv, accd[r]);
        }
        #pragma unroll
        for (int r = 0; r < 4; ++r) {
            const int row = r0 + r;
            const float sp = softplusf(accd[r]);
            const float xv = x[row * DIM + d];
            dtp[row * DIM + d]  = sp;
            dtxp[row * DIM + d] = sp * xv;
        }
    } else if (tid < 512) {
        // betgam packing: n = tid-256; beta = proj col 64+n, gamma = 320+n
        // (mapping identical to the R11-verified layout).
        const int n = tid - 256;
        #pragma unroll
        for (int r = 0; r < 4; ++r) {
            const float be = Ls[r][64 + n];
            const float ga = Ls[r][320 + n];
            betgam[(r0 + r) * NST + n] = pack_bg(be, ga);
        }
    }
}

// ---------------- scan1p: single-pass scan (R10/R11 skeleton) with prefetch
// distance stretched to 6 windows (~900-1000 cyc of issue) to cover HBM
// compulsory-miss latency; 8-slot rotation, unroll-8 keeps indices static.
// UNCHANGED this round (clean attribution of the proj rewrite).
__global__ __launch_bounds__(256, 2) void scan1p(
    const float* __restrict__ x,            // [NROWS, DIM]
    const float* __restrict__ alpha_log,    // [DIM, NST]
    const float* __restrict__ delta,        // [DIM]
    const unsigned* __restrict__ betgam,    // [NROWS, NST] packed
    const float* __restrict__ dtp,          // [NROWS, DIM]
    const float* __restrict__ dtxp,         // [NROWS, DIM]
    float* __restrict__ out)                // [NROWS, DIM]
{
    __shared__ float part[32][NST];         // 32 KB
    __shared__ float dts[LSEQ], dxs[LSEQ], xcol[LSEQ];   // 3 x 2 KB
    const int n = threadIdx.x;
    // XCD swizzle (R10-verified): XCDs 0-3 -> b=0, 4-7 -> b=1.
    const int xcd  = blockIdx.x & 7;
    const int slot = blockIdx.x >> 3;       // 0..63
    const int b = xcd >> 2;
    const int d = slot * 4 + (xcd & 3);
    const int rb = b * LSEQ;

    #pragma unroll
    for (int it = 0; it < 2; ++it) {
        const int l = n + it * 256;
        dts[l]  = dtp [(rb + l) * DIM + d];
        dxs[l]  = dtxp[(rb + l) * DIM + d];
        xcol[l] = x   [(rb + l) * DIM + d];
    }
    const float aln = -__expf(alpha_log[d * NST + n]) * LOG2E;
    const float dv  = delta[d];
    __syncthreads();                        // staging dep (global->LDS)

    float s = 0.f;
    unsigned bg[8][8];                      // 8-slot rotation, 6 windows ahead
    #pragma unroll
    for (int pw = 0; pw < 6; ++pw) {
        #pragma unroll
        for (int t = 0; t < 8; ++t)
            bg[pw][t] = betgam[(rb + pw * 8 + t) * NST + n];
    }

    #pragma unroll 8
    for (int w = 0; w < 64; ++w) {
        const int cur = w & 7;
        const int pf  = (w + 6) & 7;
        if (w + 6 < 64) {                   // issue window w+6 while computing w
            #pragma unroll
            for (int t = 0; t < 8; ++t)
                bg[pf][t] = betgam[(rb + (w + 6) * 8 + t) * NST + n];
        }
        float4 dta = *(const float4*)&dts[w * 8];
        float4 dtb = *(const float4*)&dts[w * 8 + 4];
        float4 dxa = *(const float4*)&dxs[w * 8];
        float4 dxb = *(const float4*)&dxs[w * 8 + 4];
        const float dtw[8] = {dta.x, dta.y, dta.z, dta.w, dtb.x, dtb.y, dtb.z, dtb.w};
        const float dxw[8] = {dxa.x, dxa.y, dxa.z, dxa.w, dxb.x, dxb.y, dxb.z, dxb.w};

        const int prow = (w & 3) * 8;
        #pragma unroll
        for (int t = 0; t < 8; ++t) {
            const unsigned u = bg[cur][t];
            const float be = __uint_as_float(u << 16);
            const float ga = __uint_as_float(u & 0xffff0000u);
            float a = fexp2(dtw[t] * aln);
            s = fmaf(a, s, dxw[t] * be);
            part[prow + t][n] = s * ga;     // 2-way bank alias: free
        }

        if ((w & 3) == 3) {                 // every 32 steps: reduce 32 rows x 256
            barrier_lds_only();
            const int trow = n >> 3, seg = n & 7;
            float sum = 0.f;
            #pragma unroll
            for (int k = 0; k < 32; ++k)
                sum += part[trow][seg * 32 + ((k + n) & 31)];   // measured 0-conflict
            sum += __shfl_xor(sum, 1);
            sum += __shfl_xor(sum, 2);
            sum += __shfl_xor(sum, 4);
            if (seg == 0) {
                const int l = (w >> 2) * 32 + trow;
                out[(rb + l) * DIM + d] = sum + xcol[l] * dv;
            }
            barrier_lds_only();             // WAR before next window's writes
        }
    }
}

extern "C" void kernel_launch(void* const* d_in, const int* in_sizes, int n_in,
                              void* d_out, int out_size, void* d_ws, size_t ws_size,
                              hipStream_t stream) {
    const float* x         = (const float*)d_in[0];
    const float* W_in      = (const float*)d_in[1];
    const float* W_dt      = (const float*)d_in[2];
    const float* b_dt      = (const float*)d_in[3];
    const float* alpha_log = (const float*)d_in[4];
    const float* delta     = (const float*)d_in[5];
    float* out = (float*)d_out;

    // Workspace: betgam 1MB + dtp/dtxp 2MB = 3 MB
    unsigned* betgam = (unsigned*)d_ws;
    float* dtp  = (float*)(betgam + NROWS * NST);
    float* dtxp = dtp + NROWS * DIM;

    proj_kernel<<<NROWS / 4, 576, 0, stream>>>(x, W_in, W_dt, b_dt, betgam, dtp, dtxp);
    scan1p<<<BAT * DIM, 256, 0, stream>>>(x, alpha_log, delta, betgam, dtp, dtxp, out);
}